// Round 19
// baseline (241.613 us; speedup 1.0000x reference)
//
#include <hip/hip_runtime.h>
#include <math.h>

#define NB 512
#define RR 200
#define KK1 100
#define KK2 50

__device__ __forceinline__ float sigm(float v) { return 1.0f / (1.0f + expf(-v)); }

// ---------------- nn table
__global__ void k_tab(const float* __restrict__ W1, const float* __restrict__ b1,
                      const float* __restrict__ W2, const float* __restrict__ b2,
                      float* __restrict__ tab, int OUT) {
  int n = blockIdx.x;
  __shared__ float h[8];
  if (threadIdx.x < 8) {
    float v = W1[threadIdx.x * RR + n] + b1[threadIdx.x];
    h[threadIdx.x] = v > 0.f ? v : 0.f;
  }
  __syncthreads();
  for (int j = threadIdx.x; j < OUT; j += 256) {
    float acc = b2[j];
#pragma unroll
    for (int k = 0; k < 8; k++) acc += h[k] * W2[j * 8 + k];
    tab[(size_t)n * OUT + j] = acc;
  }
}

__global__ void k_norm(const float* __restrict__ wp1, const float* __restrict__ wp2,
                       float* __restrict__ norms) {
  int t = threadIdx.x;
  float a = (t < 32) ? wp1[t] * wp1[t] : 0.f;
  float b = (t < 32) ? wp2[t] * wp2[t] : 0.f;
  for (int s = 32; s; s >>= 1) { a += __shfl_xor(a, s); b += __shfl_xor(b, s); }
  if (t == 0) { norms[0] = sqrtf(a); norms[1] = sqrtf(b); }
}

// ---------------- xt1 v6: COALESCED LDS-staged x. grid (200,8) x 128 thr.
// xs[64][204] staged with contiguous float4 streams (full 64B-line utility);
// thread owns 4 batches (bg+16r: 8 bg lanes hit 8 distinct bank-groups, 51 odd)
// x 4 outputs. Ascending-i summation (bit-exact).
__global__ __launch_bounds__(128) void k_xt1(const float* __restrict__ x,
                                             const float* __restrict__ wtab1,
                                             float* __restrict__ xt1) {
  int n = blockIdx.x, t = threadIdx.x;
  __shared__ float wsm[6400];       // 25.6 KB
  __shared__ float xs[64][204];     // 52.2 KB  => 77.8 KB total, 2 blocks/CU
  int b0g = blockIdx.y * 64;
  for (int idx = t; idx < 1600; idx += 128)
    *(float4*)&wsm[idx * 4] = *(const float4*)(wtab1 + (size_t)n * 6400 + idx * 4);
  for (int idx = t; idx < 3200; idx += 128) {
    int b = idx / 50, q = idx - b * 50;
    *(float4*)&xs[b][q * 4] =
        *(const float4*)(x + (size_t)(b0g + b) * 40000 + (size_t)n * 200 + q * 4);
  }
  __syncthreads();
  int bg = t >> 3, og = t & 7;
  float acc[4][4] = {};
  for (int i = 0; i < 200; i += 4) {
    float4 xv[4];
#pragma unroll
    for (int r = 0; r < 4; r++) xv[r] = *(const float4*)&xs[bg + 16 * r][i];
#pragma unroll
    for (int k = 0; k < 4; k++) {
      float4 w4 = *(const float4*)&wsm[(i + k) * 32 + og * 4];
#pragma unroll
      for (int r = 0; r < 4; r++) {
        float s = (&xv[r].x)[k];
        acc[r][0] += s * w4.x; acc[r][1] += s * w4.y;
        acc[r][2] += s * w4.z; acc[r][3] += s * w4.w;
      }
    }
  }
#pragma unroll
  for (int r = 0; r < 4; r++) {
    int b = b0g + bg + 16 * r;
    *(float4*)(xt1 + (size_t)b * 6400 + (size_t)n * 32 + og * 4) =
        make_float4(acc[r][0], acc[r][1], acc[r][2], acc[r][3]);
  }
}

// ---------------- stage-1 attention v11 (proven)
__global__ __launch_bounds__(1024) void k_att1(const float* __restrict__ adj,
                                               const float* __restrict__ xt1,
                                               const float* __restrict__ bias1,
                                               const float* __restrict__ wp1,
                                               const float* __restrict__ norms,
                                               float* __restrict__ h1, float* __restrict__ sc1) {
  int t = threadIdx.x;
  __shared__ float2 pvj[16][4][49];   // 25.1 KB
  __shared__ int cntS[16][4];
  int w = t >> 6, lane = t & 63;
  int rq = lane >> 4, cg = lane & 15;
  float2 biasv = *(const float2*)(bias1 + cg * 2);
  float2 wpv = *(const float2*)(wp1 + cg * 2);
  float nrm = norms[0];
  unsigned long long ltmask = (1ull << lane) - 1ull;
  int b = blockIdx.x;
  float av[4][4];
  {
    const float* abase = adj + (size_t)b * 40000 + (size_t)(w * 4) * 200;
#pragma unroll
    for (int r = 0; r < 4; r++)
#pragma unroll
      for (int s2 = 0; s2 < 4; s2++) {
        int j = lane + 64 * s2;
        av[r][s2] = (j < RR) ? __builtin_nontemporal_load(abase + r * 200 + j) : 1.0f;
      }
  }
  for (int rg = w; rg < 50; rg += 16) {
#pragma unroll
    for (int r = 0; r < 4; r++) {
      int i = rg * 4 + r;
      float e[4];
      bool nz[4];
#pragma unroll
      for (int s2 = 0; s2 < 4; s2++) {
        int j = lane + 64 * s2;
        float a = av[r][s2];
        bool keep = (j < RR) && ((j == i) || (a < 0.1f));
        float lg = (j == i) ? 1.0f : a;
        e[s2] = keep ? __expf(lg - 1.0f) : 0.f;
        nz[s2] = keep;
      }
      int base = 0;
#pragma unroll
      for (int s2 = 0; s2 < 4; s2++) {
        unsigned long long m = __ballot(nz[s2]);
        if (nz[s2]) pvj[w][r][base + __popcll(m & ltmask)] = make_float2(e[s2], (float)(lane + 64 * s2));
        base += __popcll(m);
      }
      if (lane == 0) cntS[w][r] = base;
    }
    int rg2 = rg + 16;
    if (rg2 < 50) {
      const float* abase = adj + (size_t)b * 40000 + (size_t)(rg2 * 4) * 200;
#pragma unroll
      for (int r = 0; r < 4; r++)
#pragma unroll
        for (int s2 = 0; s2 < 4; s2++) {
          int j = lane + 64 * s2;
          if (j < RR) av[r][s2] = __builtin_nontemporal_load(abase + r * 200 + j);
        }
    }
    int cnt = cntS[w][rq];
    const float* xtb = xt1 + (size_t)b * 6400 + cg * 2;
    float ax = 0.f, ay = 0.f, lsum = 0.f;
    for (int q = 0; q < cnt; q++) {
      float2 pe = pvj[w][rq][q];
      int jj = (int)pe.y;
      float2 xv = *(const float2*)(xtb + jj * 32);
      lsum += pe.x;
      ax += pe.x * xv.x;
      ay += pe.x * xv.y;
    }
    float inv = 1.0f / lsum;
    int i = rg * 4 + rq;
    float2 hv = make_float2(ax * inv + biasv.x, ay * inv + biasv.y);
    *(float2*)(h1 + ((size_t)b * RR + i) * 32 + cg * 2) = hv;
    float tt = hv.x * wpv.x + hv.y * wpv.y;
    tt += __shfl_xor(tt, 1); tt += __shfl_xor(tt, 2);
    tt += __shfl_xor(tt, 4); tt += __shfl_xor(tt, 8);
    if (cg == 0) sc1[b * RR + i] = sigm(tt / nrm);
  }
}

// ---------------- stable top-k via exact rank counting
__global__ void k_top1(const float* __restrict__ sc1, int* __restrict__ perm1,
                       float* __restrict__ vals1, float* __restrict__ out_s1) {
  int b = blockIdx.x, t = threadIdx.x;
  __shared__ float s[RR];
  for (int i = t; i < RR; i += 256) s[i] = sc1[b * RR + i];
  __syncthreads();
  for (int i = t; i < RR; i += 256) {
    float si = s[i];
    int rank = 0;
    for (int j = 0; j < RR; j++) {
      float sj = s[j];
      rank += (sj > si) || (sj == si && j < i);
    }
    if (rank < KK1) {
      perm1[b * KK1 + rank] = i;
      vals1[b * KK1 + rank] = si;
      out_s1[b * KK1 + rank] = sigm(si);
    }
  }
}

// ---------------- stage2a v2
__global__ __launch_bounds__(256) void k_stage2a(const float* __restrict__ h1,
                                                 const float* __restrict__ wtab2,
                                                 const int* __restrict__ perm1,
                                                 const float* __restrict__ vals1,
                                                 float* __restrict__ xt2,
                                                 float* __restrict__ feat) {
  int b = blockIdx.x, t = threadIdx.x;
  int kbase = blockIdx.y * 50;
  __shared__ float x1s[KK1 * 33];
  __shared__ int pk[KK1];
  __shared__ float vk[KK1];
  if (t < KK1) { pk[t] = perm1[b * KK1 + t]; vk[t] = vals1[b * KK1 + t]; }
  __syncthreads();
  for (int i = t; i < KK1 * 32; i += 256) {
    int k = i >> 5, o = i & 31;
    x1s[k * 33 + o] = h1[((size_t)b * RR + pk[k]) * 32 + o] * vk[k];
  }
  __syncthreads();
  if (blockIdx.y == 0 && t < 32) {
    float mx = -3e38f, sm = 0.f;
    for (int k = 0; k < KK1; k++) { float v = x1s[k * 33 + t]; mx = fmaxf(mx, v); sm += v; }
    feat[b * 128 + t] = mx;
    feat[b * 128 + 32 + t] = sm / 100.0f;
  }
  int w = t >> 6, lane = t & 63;
  int og = lane & 7, kq = lane >> 3;
#pragma unroll
  for (int pass = 0; pass < 2; pass++) {
    int kl = pass * 32 + w * 8 + kq;
    if (kl < 50) {
      int kg = kbase + kl;
      const float* W = wtab2 + (size_t)pk[kg] * 1024 + og * 4;
      float4 a4 = make_float4(0.f, 0.f, 0.f, 0.f);
#pragma unroll 8
      for (int ii = 0; ii < 32; ii++) {
        float4 w4 = *(const float4*)(W + ii * 32);
        float xs = x1s[kg * 33 + ii];
        a4.x += xs * w4.x; a4.y += xs * w4.y; a4.z += xs * w4.z; a4.w += xs * w4.w;
      }
      *(float4*)(xt2 + (size_t)b * 3200 + kg * 32 + og * 4) = a4;
    }
  }
}

// ---------------- wd build
__global__ __launch_bounds__(256) void k_wd(const float* __restrict__ adj,
                                            const int* __restrict__ perm1,
                                            float* __restrict__ wd) {
  int b = blockIdx.x, t = threadIdx.x;
  int g0 = blockIdx.y * 20;
  __shared__ float rowbuf[20][200];
  __shared__ int pk[KK1];
  if (t < KK1) pk[t] = perm1[b * KK1 + t];
  __syncthreads();
  for (int idx = t; idx < 4000; idx += 256) {
    int r = idx / 200, j = idx - r * 200;
    rowbuf[r][j] = adj[(size_t)b * 40000 + (size_t)pk[g0 + r] * 200 + j];
  }
  __syncthreads();
  for (int idx = t; idx < 2000; idx += 256) {
    int r = idx / 100, k2 = idx - r * 100;
    int k1 = g0 + r;
    float v;
    if (k1 == k2) v = 1.0f;
    else {
      float av = rowbuf[r][pk[k2]];
      v = (av < 0.1f) ? av : 0.0f;
    }
    wd[(size_t)b * (KK1 * KK1) + k1 * KK1 + k2] = v;
  }
}

// ---------------- stage2b v5 (fused top-k2/feat, proven)
__global__ __launch_bounds__(512) void k_stage2b(const float* __restrict__ wd,
                                                 const float* __restrict__ xt2,
                                                 const float* __restrict__ bias2,
                                                 const float* __restrict__ wp2,
                                                 const float* __restrict__ norms,
                                                 float* __restrict__ h2, float* __restrict__ sc2,
                                                 float* __restrict__ out_s2,
                                                 float* __restrict__ feat) {
  int b = blockIdx.x, t = threadIdx.x;
  __shared__ float wds[KK1][100];
  __shared__ float xts[KK1 * 32];
  __shared__ float pT[8][KK1][4];
  __shared__ int   nzidx[KK1][36];
  int w = t >> 6, lane = t & 63;
  unsigned long long ltmask = (1ull << lane) - 1ull;
  float bias_o = bias2[lane & 31];
  float wp_o = wp2[lane & 31];
  float nrm = norms[1];
  int k2a = lane;
  int k2b = lane + 64;
  bool vb = k2b < KK1;
  for (int i = t; i < KK1 * KK1; i += 512) ((float*)wds)[i] = wd[(size_t)b * (KK1 * KK1) + i];
  for (int idx = t; idx < 800; idx += 512)
    *(float4*)&xts[idx * 4] = *(const float4*)(xt2 + (size_t)b * 3200 + idx * 4);
  __syncthreads();
  for (int r = w; r < KK1; r += 8) {
    bool nz0 = (wds[r][lane] != 0.f);
    bool nz1 = (lane < KK1 - 64) && (wds[r][64 + lane] != 0.f);
    unsigned long long m0 = __ballot(nz0);
    unsigned long long m1 = __ballot(nz1);
    int c0 = __popcll(m0);
    int cnt = c0 + __popcll(m1);
    if (nz0) nzidx[r][__popcll(m0 & ltmask)] = lane;
    if (nz1) nzidx[r][c0 + __popcll(m1 & ltmask)] = 64 + lane;
    int pad = (4 - (cnt & 3)) & 3;
    if (lane < pad) nzidx[r][cnt + lane] = 0;
    if (lane == 0) nzidx[r][35] = cnt;
  }
  __syncthreads();
  for (int g = w; g < 25; g += 8) {
    int r0 = g * 4;
    float acc[4][2];
#pragma unroll
    for (int r = 0; r < 4; r++) {
      int k1 = r0 + r;
      int cnt = nzidx[k1][35];
      float s0 = 0.f, s1 = 0.f;
      for (int it = 0; it < cnt; it += 4) {
        int4 m4 = *(const int4*)&nzidx[k1][it];
        float a0 = wds[k1][m4.x];
        float a1 = (it + 1 < cnt) ? wds[k1][m4.y] : 0.f;
        float a2v = (it + 2 < cnt) ? wds[k1][m4.z] : 0.f;
        float a3 = (it + 3 < cnt) ? wds[k1][m4.w] : 0.f;
        s0 += a0 * wds[m4.x][k2a]; s1 += a0 * wds[m4.x][k2b];
        s0 += a1 * wds[m4.y][k2a]; s1 += a1 * wds[m4.y][k2b];
        s0 += a2v * wds[m4.z][k2a]; s1 += a2v * wds[m4.z][k2b];
        s0 += a3 * wds[m4.w][k2a]; s1 += a3 * wds[m4.w][k2b];
      }
      acc[r][0] = s0; acc[r][1] = s1;
    }
    float p0[4], p1[4], rs[4];
#pragma unroll
    for (int r = 0; r < 4; r++) {
      int k1 = r0 + r;
      float lv0 = (k1 == k2a) ? 1.0f : ((acc[r][0] != 0.0f) ? acc[r][0] : -1e9f);
      float lv1 = (k1 == k2b) ? 1.0f : ((acc[r][1] != 0.0f) ? acc[r][1] : -1e9f);
      float mx = vb ? fmaxf(lv0, lv1) : lv0;
      for (int s = 32; s; s >>= 1) mx = fmaxf(mx, __shfl_xor(mx, s));
      float e0 = expf(lv0 - mx);
      float e1 = vb ? expf(lv1 - mx) : 0.f;
      float ls = e0 + e1;
      for (int s = 32; s; s >>= 1) ls += __shfl_xor(ls, s);
      p0[r] = e0; p1[r] = e1; rs[r] = 1.0f / ls;
    }
    *(float4*)&pT[w][k2a][0] = make_float4(p0[0] * rs[0], p0[1] * rs[1], p0[2] * rs[2], p0[3] * rs[3]);
    if (vb) *(float4*)&pT[w][k2b][0] = make_float4(p1[0] * rs[0], p1[1] * rs[1], p1[2] * rs[2], p1[3] * rs[3]);
    int half = lane >> 5, o = lane & 31;
    float hv[4] = {0.f, 0.f, 0.f, 0.f};
    for (int jj = 0; jj < 50; jj++) {
      int j = half * 50 + jj;
      float4 pv = *(const float4*)&pT[w][j][0];
      float xv = xts[j * 32 + o];
      hv[0] += pv.x * xv; hv[1] += pv.y * xv; hv[2] += pv.z * xv; hv[3] += pv.w * xv;
    }
#pragma unroll
    for (int r = 0; r < 4; r++) hv[r] += __shfl_down(hv[r], 32);
    if (lane < 32) {
#pragma unroll
      for (int r = 0; r < 4; r++) {
        float h = hv[r] + bias_o;
        h2[((size_t)b * KK1 + (r0 + r)) * 32 + o] = h;
        float tt = h * wp_o;
        for (int s = 16; s; s >>= 1) tt += __shfl_xor(tt, s);
        if (lane == 0) sc2[b * KK1 + (r0 + r)] = sigm(tt / nrm);
      }
    }
  }
  // ---- fused top-k2 + feat[64:128]
  __syncthreads();
  float* s = (float*)&pT[0][0][0];
  int* p2 = (int*)(s + 128);
  float* v2 = (float*)(p2 + 64);
  if (t < KK1) s[t] = sc2[b * KK1 + t];
  __syncthreads();
  if (t < KK1) {
    float si = s[t];
    int rank = 0;
    for (int j = 0; j < KK1; j++) {
      float sj = s[j];
      rank += (sj > si) || (sj == si && j < t);
    }
    if (rank < KK2) {
      p2[rank] = t;
      v2[rank] = si;
      out_s2[b * KK2 + rank] = sigm(si);
    }
  }
  __syncthreads();
  if (t < 32) {
    float mx = -3e38f, sm = 0.f;
    for (int k = 0; k < KK2; k++) {
      float v = h2[((size_t)b * KK1 + p2[k]) * 32 + t] * v2[k];
      mx = fmaxf(mx, v);
      sm += v;
    }
    feat[b * 128 + 64 + t] = mx;
    feat[b * 128 + 96 + t] = sm / 50.0f;
  }
}

// ---------------- y1 = leaky(feat @ Wm1.T + bm1)
__global__ void k_mlp1(const float* __restrict__ feat, const float* __restrict__ Wm1,
                       const float* __restrict__ bm1, float* __restrict__ y1) {
  __shared__ float Wt[128 * 32];
  __shared__ float f[8][128];
  int t = threadIdx.x;
  for (int i = t; i < 4096; i += 256) { int c = i >> 7, d = i & 127; Wt[d * 32 + c] = Wm1[i]; }
  int b0 = blockIdx.x * 8;
  for (int i = t; i < 1024; i += 256) f[i >> 7][i & 127] = feat[b0 * 128 + i];
  __syncthreads();
  int bl = t >> 5, c = t & 31;
  float acc = bm1[c];
#pragma unroll 4
  for (int d = 0; d < 128; d++) acc += f[bl][d] * Wt[d * 32 + c];
  y1[(b0 + bl) * 32 + c] = acc > 0.f ? acc : 0.01f * acc;
}

// ---------------- BN stats
__global__ void k_bn(const float* __restrict__ y, int C, float* __restrict__ stats) {
  int c = blockIdx.x, t = threadIdx.x;
  __shared__ float ys[512];
  __shared__ float red[8];
  ys[t] = y[(size_t)t * C + c];
  ys[t + 256] = y[(size_t)(t + 256) * C + c];
  __syncthreads();
  float s = ys[t] + ys[t + 256];
  for (int d = 32; d; d >>= 1) s += __shfl_xor(s, d);
  if ((t & 63) == 0) red[t >> 6] = s;
  __syncthreads();
  float mu = (red[0] + red[1] + red[2] + red[3]) * (1.0f / 512.0f);
  float d0 = ys[t] - mu, d1 = ys[t + 256] - mu;
  float v = d0 * d0 + d1 * d1;
  for (int d = 32; d; d >>= 1) v += __shfl_xor(v, d);
  if ((t & 63) == 0) red[4 + (t >> 6)] = v;
  __syncthreads();
  if (t == 0) {
    float var = (red[4] + red[5] + red[6] + red[7]) * (1.0f / 512.0f);
    stats[c] = mu;
    stats[C + c] = rsqrtf(var + 1e-5f);
  }
}

// ---------------- y2 = leaky(norm(y1) @ Wm2.T + bm2)
__global__ void k_mlp2(const float* __restrict__ y1, const float* __restrict__ st1,
                       const float* __restrict__ g1, const float* __restrict__ be1,
                       const float* __restrict__ Wm2, const float* __restrict__ bm2,
                       float* __restrict__ y2) {
  __shared__ float yn[32];
  int b = blockIdx.x, t = threadIdx.x;
  if (t < 32) {
    float v = y1[b * 32 + t];
    yn[t] = g1[t] * (v - st1[t]) * st1[32 + t] + be1[t];
  }
  __syncthreads();
  for (int c = t; c < 512; c += 256) {
    float acc = bm2[c];
#pragma unroll
    for (int k = 0; k < 32; k++) acc += yn[k] * Wm2[c * 32 + k];
    y2[(size_t)b * 512 + c] = acc > 0.f ? acc : 0.01f * acc;
  }
}

// ---------------- final: logits + log_softmax
__global__ void k_final(const float* __restrict__ y2, const float* __restrict__ st2,
                        const float* __restrict__ g2, const float* __restrict__ be2,
                        const float* __restrict__ Ws, const float* __restrict__ bs,
                        float* __restrict__ out) {
  int w = threadIdx.x >> 6, lane = threadIdx.x & 63;
  int b = blockIdx.x * 4 + w;
  float z0 = 0.f, z1 = 0.f;
  for (int c = lane; c < 512; c += 64) {
    float v = g2[c] * (y2[(size_t)b * 512 + c] - st2[c]) * st2[512 + c] + be2[c];
    z0 += v * Ws[c];
    z1 += v * Ws[512 + c];
  }
  for (int s = 32; s; s >>= 1) { z0 += __shfl_xor(z0, s); z1 += __shfl_xor(z1, s); }
  if (lane == 0) {
    z0 += bs[0];
    z1 += bs[1];
    float m = fmaxf(z0, z1);
    float lse = m + logf(expf(z0 - m) + expf(z1 - m));
    out[b * 2] = z0 - lse;
    out[b * 2 + 1] = z1 - lse;
  }
}

__global__ void k_copy(const float* __restrict__ wp1, const float* __restrict__ wp2,
                       float* __restrict__ out) {
  int t = threadIdx.x;
  if (t < 32) out[1024 + t] = wp1[t];
  else if (t < 64) out[1056 + (t - 32)] = wp2[t - 32];
}

extern "C" void kernel_launch(void* const* d_in, const int* in_sizes, int n_in,
                              void* d_out, int out_size, void* d_ws, size_t ws_size,
                              hipStream_t stream) {
  const float* x    = (const float*)d_in[0];
  const float* adj  = (const float*)d_in[1];
  const float* W1a  = (const float*)d_in[3];
  const float* b1a  = (const float*)d_in[4];
  const float* W2a  = (const float*)d_in[5];
  const float* b2a  = (const float*)d_in[6];
  const float* bias1= (const float*)d_in[7];
  const float* W1b  = (const float*)d_in[8];
  const float* b1b  = (const float*)d_in[9];
  const float* W2b  = (const float*)d_in[10];
  const float* b2b  = (const float*)d_in[11];
  const float* bias2= (const float*)d_in[12];
  const float* wp1  = (const float*)d_in[13];
  const float* wp2  = (const float*)d_in[14];
  const float* Wm1  = (const float*)d_in[15];
  const float* bm1  = (const float*)d_in[16];
  const float* g1   = (const float*)d_in[17];
  const float* be1  = (const float*)d_in[18];
  const float* Wm2  = (const float*)d_in[19];
  const float* bm2  = (const float*)d_in[20];
  const float* g2   = (const float*)d_in[21];
  const float* be2  = (const float*)d_in[22];
  const float* Ws   = (const float*)d_in[23];
  const float* bs   = (const float*)d_in[24];
  float* out = (float*)d_out;

  float* ws = (float*)d_ws;
  float* WTAB1 = ws;                       // 1,280,000
  float* WTAB2 = WTAB1 + 1280000;          // 204,800
  float* NORMS = WTAB2 + 204800;           // 16
  float* XT1   = NORMS + 16;               // 3,276,800
  float* H1    = XT1 + 3276800;            // 3,276,800
  float* SC1   = H1 + 3276800;             // 102,400
  float* VALS1 = SC1 + 102400;             // 51,200
  int*   PERM1 = (int*)(VALS1 + 51200);    // 51,200
  float* XT2   = (float*)(PERM1 + 51200);  // 1,638,400
  float* WD    = XT2 + 1638400;            // 5,120,000
  float* H2    = WD + 5120000;             // 1,638,400
  float* SC2   = H2 + 1638400;             // 51,200
  float* FEAT  = SC2 + 51200;              // 65,536
  float* Y1    = FEAT + 65536;             // 16,384
  float* ST1   = Y1 + 16384;               // 64
  float* Y2    = ST1 + 64;                 // 262,144
  float* ST2   = Y2 + 262144;              // 1,024

  k_tab<<<200, 256, 0, stream>>>(W1a, b1a, W2a, b2a, WTAB1, 6400);
  k_tab<<<200, 256, 0, stream>>>(W1b, b1b, W2b, b2b, WTAB2, 1024);
  k_norm<<<1, 64, 0, stream>>>(wp1, wp2, NORMS);
  k_xt1<<<dim3(200, 8), 128, 0, stream>>>(x, WTAB1, XT1);
  k_att1<<<512, 1024, 0, stream>>>(adj, XT1, bias1, wp1, NORMS, H1, SC1);
  k_top1<<<512, 256, 0, stream>>>(SC1, PERM1, VALS1, out + 1088);
  k_stage2a<<<dim3(512, 2), 256, 0, stream>>>(H1, WTAB2, PERM1, VALS1, XT2, FEAT);
  k_wd<<<dim3(512, 5), 256, 0, stream>>>(adj, PERM1, WD);
  k_stage2b<<<512, 512, 0, stream>>>(WD, XT2, bias2, wp2, NORMS, H2, SC2,
                                     out + 52288, FEAT);
  k_mlp1<<<64, 256, 0, stream>>>(FEAT, Wm1, bm1, Y1);
  k_bn<<<32, 256, 0, stream>>>(Y1, 32, ST1);
  k_mlp2<<<512, 256, 0, stream>>>(Y1, ST1, g1, be1, Wm2, bm2, Y2);
  k_bn<<<512, 256, 0, stream>>>(Y2, 512, ST2);
  k_final<<<128, 256, 0, stream>>>(Y2, ST2, g2, be2, Ws, bs, out);
  k_copy<<<1, 64, 0, stream>>>(wp1, wp2, out);
}

// Round 20
// 202.270 us; speedup vs baseline: 1.1945x; 1.1945x over previous
//
#include <hip/hip_runtime.h>
#include <math.h>

#define NB 512
#define RR 200
#define KK1 100
#define KK2 50

__device__ __forceinline__ float sigm(float v) { return 1.0f / (1.0f + expf(-v)); }

// ---------------- nn table
__global__ void k_tab(const float* __restrict__ W1, const float* __restrict__ b1,
                      const float* __restrict__ W2, const float* __restrict__ b2,
                      float* __restrict__ tab, int OUT) {
  int n = blockIdx.x;
  __shared__ float h[8];
  if (threadIdx.x < 8) {
    float v = W1[threadIdx.x * RR + n] + b1[threadIdx.x];
    h[threadIdx.x] = v > 0.f ? v : 0.f;
  }
  __syncthreads();
  for (int j = threadIdx.x; j < OUT; j += 256) {
    float acc = b2[j];
#pragma unroll
    for (int k = 0; k < 8; k++) acc += h[k] * W2[j * 8 + k];
    tab[(size_t)n * OUT + j] = acc;
  }
}

__global__ void k_norm(const float* __restrict__ wp1, const float* __restrict__ wp2,
                       float* __restrict__ norms) {
  int t = threadIdx.x;
  float a = (t < 32) ? wp1[t] * wp1[t] : 0.f;
  float b = (t < 32) ? wp2[t] * wp2[t] : 0.f;
  for (int s = 32; s; s >>= 1) { a += __shfl_xor(a, s); b += __shfl_xor(b, s); }
  if (t == 0) { norms[0] = sqrtf(a); norms[1] = sqrtf(b); }
}

// ---------------- xt1 v4 (round-14/18 proven best: mega-block, ~56 us)
__global__ __launch_bounds__(1024) void k_xt1(const float* __restrict__ x,
                                              const float* __restrict__ wtab1,
                                              float* __restrict__ xt1) {
  int n = blockIdx.x, t = threadIdx.x;
  __shared__ float wsm[6400];   // 25.6 KB
  for (int idx = t; idx < 1600; idx += 1024)
    *(float4*)&wsm[idx * 4] = *(const float4*)(wtab1 + (size_t)n * 6400 + idx * 4);
  __syncthreads();
  int bg = t >> 3, og = t & 7;
  int b0 = bg * 4;
  const float* xp = x + (size_t)b0 * 40000 + (size_t)n * 200;
  float acc[4][4] = {};
  float4 A[4], Bf[4], N0[4] = {}, N1[4] = {};
#pragma unroll
  for (int r = 0; r < 4; r++) A[r] = *(const float4*)(xp + (size_t)r * 40000);
#pragma unroll
  for (int r = 0; r < 4; r++) Bf[r] = *(const float4*)(xp + (size_t)r * 40000 + 4);
  for (int g = 0; g < 50; g += 2) {
    int i = g * 4;
    if (g + 2 < 50) {
#pragma unroll
      for (int r = 0; r < 4; r++) N0[r] = *(const float4*)(xp + (size_t)r * 40000 + i + 8);
#pragma unroll
      for (int r = 0; r < 4; r++) N1[r] = *(const float4*)(xp + (size_t)r * 40000 + i + 12);
    }
#pragma unroll
    for (int k = 0; k < 4; k++) {
      float4 w4 = *(const float4*)&wsm[(i + k) * 32 + og * 4];
#pragma unroll
      for (int r = 0; r < 4; r++) {
        float xs = (&A[r].x)[k];
        acc[r][0] += xs * w4.x; acc[r][1] += xs * w4.y;
        acc[r][2] += xs * w4.z; acc[r][3] += xs * w4.w;
      }
    }
#pragma unroll
    for (int k = 0; k < 4; k++) {
      float4 w4 = *(const float4*)&wsm[(i + 4 + k) * 32 + og * 4];
#pragma unroll
      for (int r = 0; r < 4; r++) {
        float xs = (&Bf[r].x)[k];
        acc[r][0] += xs * w4.x; acc[r][1] += xs * w4.y;
        acc[r][2] += xs * w4.z; acc[r][3] += xs * w4.w;
      }
    }
#pragma unroll
    for (int r = 0; r < 4; r++) { A[r] = N0[r]; Bf[r] = N1[r]; }
  }
#pragma unroll
  for (int r = 0; r < 4; r++)
    *(float4*)(xt1 + (size_t)(b0 + r) * 6400 + (size_t)n * 32 + og * 4) =
        make_float4(acc[r][0], acc[r][1], acc[r][2], acc[r][3]);
}

// ---------------- stage-1 attention v11 (proven)
__global__ __launch_bounds__(1024) void k_att1(const float* __restrict__ adj,
                                               const float* __restrict__ xt1,
                                               const float* __restrict__ bias1,
                                               const float* __restrict__ wp1,
                                               const float* __restrict__ norms,
                                               float* __restrict__ h1, float* __restrict__ sc1) {
  int t = threadIdx.x;
  __shared__ float2 pvj[16][4][49];   // 25.1 KB
  __shared__ int cntS[16][4];
  int w = t >> 6, lane = t & 63;
  int rq = lane >> 4, cg = lane & 15;
  float2 biasv = *(const float2*)(bias1 + cg * 2);
  float2 wpv = *(const float2*)(wp1 + cg * 2);
  float nrm = norms[0];
  unsigned long long ltmask = (1ull << lane) - 1ull;
  int b = blockIdx.x;
  float av[4][4];
  {
    const float* abase = adj + (size_t)b * 40000 + (size_t)(w * 4) * 200;
#pragma unroll
    for (int r = 0; r < 4; r++)
#pragma unroll
      for (int s2 = 0; s2 < 4; s2++) {
        int j = lane + 64 * s2;
        av[r][s2] = (j < RR) ? __builtin_nontemporal_load(abase + r * 200 + j) : 1.0f;
      }
  }
  for (int rg = w; rg < 50; rg += 16) {
#pragma unroll
    for (int r = 0; r < 4; r++) {
      int i = rg * 4 + r;
      float e[4];
      bool nz[4];
#pragma unroll
      for (int s2 = 0; s2 < 4; s2++) {
        int j = lane + 64 * s2;
        float a = av[r][s2];
        bool keep = (j < RR) && ((j == i) || (a < 0.1f));
        float lg = (j == i) ? 1.0f : a;
        e[s2] = keep ? __expf(lg - 1.0f) : 0.f;
        nz[s2] = keep;
      }
      int base = 0;
#pragma unroll
      for (int s2 = 0; s2 < 4; s2++) {
        unsigned long long m = __ballot(nz[s2]);
        if (nz[s2]) pvj[w][r][base + __popcll(m & ltmask)] = make_float2(e[s2], (float)(lane + 64 * s2));
        base += __popcll(m);
      }
      if (lane == 0) cntS[w][r] = base;
    }
    int rg2 = rg + 16;
    if (rg2 < 50) {
      const float* abase = adj + (size_t)b * 40000 + (size_t)(rg2 * 4) * 200;
#pragma unroll
      for (int r = 0; r < 4; r++)
#pragma unroll
        for (int s2 = 0; s2 < 4; s2++) {
          int j = lane + 64 * s2;
          if (j < RR) av[r][s2] = __builtin_nontemporal_load(abase + r * 200 + j);
        }
    }
    int cnt = cntS[w][rq];
    const float* xtb = xt1 + (size_t)b * 6400 + cg * 2;
    float ax = 0.f, ay = 0.f, lsum = 0.f;
    for (int q = 0; q < cnt; q++) {
      float2 pe = pvj[w][rq][q];
      int jj = (int)pe.y;
      float2 xv = *(const float2*)(xtb + jj * 32);
      lsum += pe.x;
      ax += pe.x * xv.x;
      ay += pe.x * xv.y;
    }
    float inv = 1.0f / lsum;
    int i = rg * 4 + rq;
    float2 hv = make_float2(ax * inv + biasv.x, ay * inv + biasv.y);
    *(float2*)(h1 + ((size_t)b * RR + i) * 32 + cg * 2) = hv;
    float tt = hv.x * wpv.x + hv.y * wpv.y;
    tt += __shfl_xor(tt, 1); tt += __shfl_xor(tt, 2);
    tt += __shfl_xor(tt, 4); tt += __shfl_xor(tt, 8);
    if (cg == 0) sc1[b * RR + i] = sigm(tt / nrm);
  }
}

// ---------------- stable top-k via exact rank counting
__global__ void k_top1(const float* __restrict__ sc1, int* __restrict__ perm1,
                       float* __restrict__ vals1, float* __restrict__ out_s1) {
  int b = blockIdx.x, t = threadIdx.x;
  __shared__ float s[RR];
  for (int i = t; i < RR; i += 256) s[i] = sc1[b * RR + i];
  __syncthreads();
  for (int i = t; i < RR; i += 256) {
    float si = s[i];
    int rank = 0;
    for (int j = 0; j < RR; j++) {
      float sj = s[j];
      rank += (sj > si) || (sj == si && j < i);
    }
    if (rank < KK1) {
      perm1[b * KK1 + rank] = i;
      vals1[b * KK1 + rank] = si;
      out_s1[b * KK1 + rank] = sigm(si);
    }
  }
}

// ---------------- stage2a v2
__global__ __launch_bounds__(256) void k_stage2a(const float* __restrict__ h1,
                                                 const float* __restrict__ wtab2,
                                                 const int* __restrict__ perm1,
                                                 const float* __restrict__ vals1,
                                                 float* __restrict__ xt2,
                                                 float* __restrict__ feat) {
  int b = blockIdx.x, t = threadIdx.x;
  int kbase = blockIdx.y * 50;
  __shared__ float x1s[KK1 * 33];
  __shared__ int pk[KK1];
  __shared__ float vk[KK1];
  if (t < KK1) { pk[t] = perm1[b * KK1 + t]; vk[t] = vals1[b * KK1 + t]; }
  __syncthreads();
  for (int i = t; i < KK1 * 32; i += 256) {
    int k = i >> 5, o = i & 31;
    x1s[k * 33 + o] = h1[((size_t)b * RR + pk[k]) * 32 + o] * vk[k];
  }
  __syncthreads();
  if (blockIdx.y == 0 && t < 32) {
    float mx = -3e38f, sm = 0.f;
    for (int k = 0; k < KK1; k++) { float v = x1s[k * 33 + t]; mx = fmaxf(mx, v); sm += v; }
    feat[b * 128 + t] = mx;
    feat[b * 128 + 32 + t] = sm / 100.0f;
  }
  int w = t >> 6, lane = t & 63;
  int og = lane & 7, kq = lane >> 3;
#pragma unroll
  for (int pass = 0; pass < 2; pass++) {
    int kl = pass * 32 + w * 8 + kq;
    if (kl < 50) {
      int kg = kbase + kl;
      const float* W = wtab2 + (size_t)pk[kg] * 1024 + og * 4;
      float4 a4 = make_float4(0.f, 0.f, 0.f, 0.f);
#pragma unroll 8
      for (int ii = 0; ii < 32; ii++) {
        float4 w4 = *(const float4*)(W + ii * 32);
        float xs = x1s[kg * 33 + ii];
        a4.x += xs * w4.x; a4.y += xs * w4.y; a4.z += xs * w4.z; a4.w += xs * w4.w;
      }
      *(float4*)(xt2 + (size_t)b * 3200 + kg * 32 + og * 4) = a4;
    }
  }
}

// ---------------- wd build
__global__ __launch_bounds__(256) void k_wd(const float* __restrict__ adj,
                                            const int* __restrict__ perm1,
                                            float* __restrict__ wd) {
  int b = blockIdx.x, t = threadIdx.x;
  int g0 = blockIdx.y * 20;
  __shared__ float rowbuf[20][200];
  __shared__ int pk[KK1];
  if (t < KK1) pk[t] = perm1[b * KK1 + t];
  __syncthreads();
  for (int idx = t; idx < 4000; idx += 256) {
    int r = idx / 200, j = idx - r * 200;
    rowbuf[r][j] = adj[(size_t)b * 40000 + (size_t)pk[g0 + r] * 200 + j];
  }
  __syncthreads();
  for (int idx = t; idx < 2000; idx += 256) {
    int r = idx / 100, k2 = idx - r * 100;
    int k1 = g0 + r;
    float v;
    if (k1 == k2) v = 1.0f;
    else {
      float av = rowbuf[r][pk[k2]];
      v = (av < 0.1f) ? av : 0.0f;
    }
    wd[(size_t)b * (KK1 * KK1) + k1 * KK1 + k2] = v;
  }
}

// ---------------- stage2b v5 (fused top-k2/feat, proven)
__global__ __launch_bounds__(512) void k_stage2b(const float* __restrict__ wd,
                                                 const float* __restrict__ xt2,
                                                 const float* __restrict__ bias2,
                                                 const float* __restrict__ wp2,
                                                 const float* __restrict__ norms,
                                                 float* __restrict__ h2, float* __restrict__ sc2,
                                                 float* __restrict__ out_s2,
                                                 float* __restrict__ feat) {
  int b = blockIdx.x, t = threadIdx.x;
  __shared__ float wds[KK1][100];
  __shared__ float xts[KK1 * 32];
  __shared__ float pT[8][KK1][4];
  __shared__ int   nzidx[KK1][36];
  int w = t >> 6, lane = t & 63;
  unsigned long long ltmask = (1ull << lane) - 1ull;
  float bias_o = bias2[lane & 31];
  float wp_o = wp2[lane & 31];
  float nrm = norms[1];
  int k2a = lane;
  int k2b = lane + 64;
  bool vb = k2b < KK1;
  for (int i = t; i < KK1 * KK1; i += 512) ((float*)wds)[i] = wd[(size_t)b * (KK1 * KK1) + i];
  for (int idx = t; idx < 800; idx += 512)
    *(float4*)&xts[idx * 4] = *(const float4*)(xt2 + (size_t)b * 3200 + idx * 4);
  __syncthreads();
  for (int r = w; r < KK1; r += 8) {
    bool nz0 = (wds[r][lane] != 0.f);
    bool nz1 = (lane < KK1 - 64) && (wds[r][64 + lane] != 0.f);
    unsigned long long m0 = __ballot(nz0);
    unsigned long long m1 = __ballot(nz1);
    int c0 = __popcll(m0);
    int cnt = c0 + __popcll(m1);
    if (nz0) nzidx[r][__popcll(m0 & ltmask)] = lane;
    if (nz1) nzidx[r][c0 + __popcll(m1 & ltmask)] = 64 + lane;
    int pad = (4 - (cnt & 3)) & 3;
    if (lane < pad) nzidx[r][cnt + lane] = 0;
    if (lane == 0) nzidx[r][35] = cnt;
  }
  __syncthreads();
  for (int g = w; g < 25; g += 8) {
    int r0 = g * 4;
    float acc[4][2];
#pragma unroll
    for (int r = 0; r < 4; r++) {
      int k1 = r0 + r;
      int cnt = nzidx[k1][35];
      float s0 = 0.f, s1 = 0.f;
      for (int it = 0; it < cnt; it += 4) {
        int4 m4 = *(const int4*)&nzidx[k1][it];
        float a0 = wds[k1][m4.x];
        float a1 = (it + 1 < cnt) ? wds[k1][m4.y] : 0.f;
        float a2v = (it + 2 < cnt) ? wds[k1][m4.z] : 0.f;
        float a3 = (it + 3 < cnt) ? wds[k1][m4.w] : 0.f;
        s0 += a0 * wds[m4.x][k2a]; s1 += a0 * wds[m4.x][k2b];
        s0 += a1 * wds[m4.y][k2a]; s1 += a1 * wds[m4.y][k2b];
        s0 += a2v * wds[m4.z][k2a]; s1 += a2v * wds[m4.z][k2b];
        s0 += a3 * wds[m4.w][k2a]; s1 += a3 * wds[m4.w][k2b];
      }
      acc[r][0] = s0; acc[r][1] = s1;
    }
    float p0[4], p1[4], rs[4];
#pragma unroll
    for (int r = 0; r < 4; r++) {
      int k1 = r0 + r;
      float lv0 = (k1 == k2a) ? 1.0f : ((acc[r][0] != 0.0f) ? acc[r][0] : -1e9f);
      float lv1 = (k1 == k2b) ? 1.0f : ((acc[r][1] != 0.0f) ? acc[r][1] : -1e9f);
      float mx = vb ? fmaxf(lv0, lv1) : lv0;
      for (int s = 32; s; s >>= 1) mx = fmaxf(mx, __shfl_xor(mx, s));
      float e0 = expf(lv0 - mx);
      float e1 = vb ? expf(lv1 - mx) : 0.f;
      float ls = e0 + e1;
      for (int s = 32; s; s >>= 1) ls += __shfl_xor(ls, s);
      p0[r] = e0; p1[r] = e1; rs[r] = 1.0f / ls;
    }
    *(float4*)&pT[w][k2a][0] = make_float4(p0[0] * rs[0], p0[1] * rs[1], p0[2] * rs[2], p0[3] * rs[3]);
    if (vb) *(float4*)&pT[w][k2b][0] = make_float4(p1[0] * rs[0], p1[1] * rs[1], p1[2] * rs[2], p1[3] * rs[3]);
    int half = lane >> 5, o = lane & 31;
    float hv[4] = {0.f, 0.f, 0.f, 0.f};
    for (int jj = 0; jj < 50; jj++) {
      int j = half * 50 + jj;
      float4 pv = *(const float4*)&pT[w][j][0];
      float xv = xts[j * 32 + o];
      hv[0] += pv.x * xv; hv[1] += pv.y * xv; hv[2] += pv.z * xv; hv[3] += pv.w * xv;
    }
#pragma unroll
    for (int r = 0; r < 4; r++) hv[r] += __shfl_down(hv[r], 32);
    if (lane < 32) {
#pragma unroll
      for (int r = 0; r < 4; r++) {
        float h = hv[r] + bias_o;
        h2[((size_t)b * KK1 + (r0 + r)) * 32 + o] = h;
        float tt = h * wp_o;
        for (int s = 16; s; s >>= 1) tt += __shfl_xor(tt, s);
        if (lane == 0) sc2[b * KK1 + (r0 + r)] = sigm(tt / nrm);
      }
    }
  }
  // ---- fused top-k2 + feat[64:128]
  __syncthreads();
  float* s = (float*)&pT[0][0][0];
  int* p2 = (int*)(s + 128);
  float* v2 = (float*)(p2 + 64);
  if (t < KK1) s[t] = sc2[b * KK1 + t];
  __syncthreads();
  if (t < KK1) {
    float si = s[t];
    int rank = 0;
    for (int j = 0; j < KK1; j++) {
      float sj = s[j];
      rank += (sj > si) || (sj == si && j < t);
    }
    if (rank < KK2) {
      p2[rank] = t;
      v2[rank] = si;
      out_s2[b * KK2 + rank] = sigm(si);
    }
  }
  __syncthreads();
  if (t < 32) {
    float mx = -3e38f, sm = 0.f;
    for (int k = 0; k < KK2; k++) {
      float v = h2[((size_t)b * KK1 + p2[k]) * 32 + t] * v2[k];
      mx = fmaxf(mx, v);
      sm += v;
    }
    feat[b * 128 + 64 + t] = mx;
    feat[b * 128 + 96 + t] = sm / 50.0f;
  }
}

// ---------------- y1 = leaky(feat @ Wm1.T + bm1)
__global__ void k_mlp1(const float* __restrict__ feat, const float* __restrict__ Wm1,
                       const float* __restrict__ bm1, float* __restrict__ y1) {
  __shared__ float Wt[128 * 32];
  __shared__ float f[8][128];
  int t = threadIdx.x;
  for (int i = t; i < 4096; i += 256) { int c = i >> 7, d = i & 127; Wt[d * 32 + c] = Wm1[i]; }
  int b0 = blockIdx.x * 8;
  for (int i = t; i < 1024; i += 256) f[i >> 7][i & 127] = feat[b0 * 128 + i];
  __syncthreads();
  int bl = t >> 5, c = t & 31;
  float acc = bm1[c];
#pragma unroll 4
  for (int d = 0; d < 128; d++) acc += f[bl][d] * Wt[d * 32 + c];
  y1[(b0 + bl) * 32 + c] = acc > 0.f ? acc : 0.01f * acc;
}

// ---------------- BN stats
__global__ void k_bn(const float* __restrict__ y, int C, float* __restrict__ stats) {
  int c = blockIdx.x, t = threadIdx.x;
  __shared__ float ys[512];
  __shared__ float red[8];
  ys[t] = y[(size_t)t * C + c];
  ys[t + 256] = y[(size_t)(t + 256) * C + c];
  __syncthreads();
  float s = ys[t] + ys[t + 256];
  for (int d = 32; d; d >>= 1) s += __shfl_xor(s, d);
  if ((t & 63) == 0) red[t >> 6] = s;
  __syncthreads();
  float mu = (red[0] + red[1] + red[2] + red[3]) * (1.0f / 512.0f);
  float d0 = ys[t] - mu, d1 = ys[t + 256] - mu;
  float v = d0 * d0 + d1 * d1;
  for (int d = 32; d; d >>= 1) v += __shfl_xor(v, d);
  if ((t & 63) == 0) red[4 + (t >> 6)] = v;
  __syncthreads();
  if (t == 0) {
    float var = (red[4] + red[5] + red[6] + red[7]) * (1.0f / 512.0f);
    stats[c] = mu;
    stats[C + c] = rsqrtf(var + 1e-5f);
  }
}

// ---------------- y2 = leaky(norm(y1) @ Wm2.T + bm2)
__global__ void k_mlp2(const float* __restrict__ y1, const float* __restrict__ st1,
                       const float* __restrict__ g1, const float* __restrict__ be1,
                       const float* __restrict__ Wm2, const float* __restrict__ bm2,
                       float* __restrict__ y2) {
  __shared__ float yn[32];
  int b = blockIdx.x, t = threadIdx.x;
  if (t < 32) {
    float v = y1[b * 32 + t];
    yn[t] = g1[t] * (v - st1[t]) * st1[32 + t] + be1[t];
  }
  __syncthreads();
  for (int c = t; c < 512; c += 256) {
    float acc = bm2[c];
#pragma unroll
    for (int k = 0; k < 32; k++) acc += yn[k] * Wm2[c * 32 + k];
    y2[(size_t)b * 512 + c] = acc > 0.f ? acc : 0.01f * acc;
  }
}

// ---------------- final: logits + log_softmax
__global__ void k_final(const float* __restrict__ y2, const float* __restrict__ st2,
                        const float* __restrict__ g2, const float* __restrict__ be2,
                        const float* __restrict__ Ws, const float* __restrict__ bs,
                        float* __restrict__ out) {
  int w = threadIdx.x >> 6, lane = threadIdx.x & 63;
  int b = blockIdx.x * 4 + w;
  float z0 = 0.f, z1 = 0.f;
  for (int c = lane; c < 512; c += 64) {
    float v = g2[c] * (y2[(size_t)b * 512 + c] - st2[c]) * st2[512 + c] + be2[c];
    z0 += v * Ws[c];
    z1 += v * Ws[512 + c];
  }
  for (int s = 32; s; s >>= 1) { z0 += __shfl_xor(z0, s); z1 += __shfl_xor(z1, s); }
  if (lane == 0) {
    z0 += bs[0];
    z1 += bs[1];
    float m = fmaxf(z0, z1);
    float lse = m + logf(expf(z0 - m) + expf(z1 - m));
    out[b * 2] = z0 - lse;
    out[b * 2 + 1] = z1 - lse;
  }
}

__global__ void k_copy(const float* __restrict__ wp1, const float* __restrict__ wp2,
                       float* __restrict__ out) {
  int t = threadIdx.x;
  if (t < 32) out[1024 + t] = wp1[t];
  else if (t < 64) out[1056 + (t - 32)] = wp2[t - 32];
}

extern "C" void kernel_launch(void* const* d_in, const int* in_sizes, int n_in,
                              void* d_out, int out_size, void* d_ws, size_t ws_size,
                              hipStream_t stream) {
  const float* x    = (const float*)d_in[0];
  const float* adj  = (const float*)d_in[1];
  const float* W1a  = (const float*)d_in[3];
  const float* b1a  = (const float*)d_in[4];
  const float* W2a  = (const float*)d_in[5];
  const float* b2a  = (const float*)d_in[6];
  const float* bias1= (const float*)d_in[7];
  const float* W1b  = (const float*)d_in[8];
  const float* b1b  = (const float*)d_in[9];
  const float* W2b  = (const float*)d_in[10];
  const float* b2b  = (const float*)d_in[11];
  const float* bias2= (const float*)d_in[12];
  const float* wp1  = (const float*)d_in[13];
  const float* wp2  = (const float*)d_in[14];
  const float* Wm1  = (const float*)d_in[15];
  const float* bm1  = (const float*)d_in[16];
  const float* g1   = (const float*)d_in[17];
  const float* be1  = (const float*)d_in[18];
  const float* Wm2  = (const float*)d_in[19];
  const float* bm2  = (const float*)d_in[20];
  const float* g2   = (const float*)d_in[21];
  const float* be2  = (const float*)d_in[22];
  const float* Ws   = (const float*)d_in[23];
  const float* bs   = (const float*)d_in[24];
  float* out = (float*)d_out;

  float* ws = (float*)d_ws;
  float* WTAB1 = ws;                       // 1,280,000
  float* WTAB2 = WTAB1 + 1280000;          // 204,800
  float* NORMS = WTAB2 + 204800;           // 16
  float* XT1   = NORMS + 16;               // 3,276,800
  float* H1    = XT1 + 3276800;            // 3,276,800
  float* SC1   = H1 + 3276800;             // 102,400
  float* VALS1 = SC1 + 102400;             // 51,200
  int*   PERM1 = (int*)(VALS1 + 51200);    // 51,200
  float* XT2   = (float*)(PERM1 + 51200);  // 1,638,400
  float* WD    = XT2 + 1638400;            // 5,120,000
  float* H2    = WD + 5120000;             // 1,638,400
  float* SC2   = H2 + 1638400;             // 51,200
  float* FEAT  = SC2 + 51200;              // 65,536
  float* Y1    = FEAT + 65536;             // 16,384
  float* ST1   = Y1 + 16384;               // 64
  float* Y2    = ST1 + 64;                 // 262,144
  float* ST2   = Y2 + 262144;              // 1,024

  k_tab<<<200, 256, 0, stream>>>(W1a, b1a, W2a, b2a, WTAB1, 6400);
  k_tab<<<200, 256, 0, stream>>>(W1b, b1b, W2b, b2b, WTAB2, 1024);
  k_norm<<<1, 64, 0, stream>>>(wp1, wp2, NORMS);
  k_xt1<<<200, 1024, 0, stream>>>(x, WTAB1, XT1);
  k_att1<<<512, 1024, 0, stream>>>(adj, XT1, bias1, wp1, NORMS, H1, SC1);
  k_top1<<<512, 256, 0, stream>>>(SC1, PERM1, VALS1, out + 1088);
  k_stage2a<<<dim3(512, 2), 256, 0, stream>>>(H1, WTAB2, PERM1, VALS1, XT2, FEAT);
  k_wd<<<dim3(512, 5), 256, 0, stream>>>(adj, PERM1, WD);
  k_stage2b<<<512, 512, 0, stream>>>(WD, XT2, bias2, wp2, NORMS, H2, SC2,
                                     out + 52288, FEAT);
  k_mlp1<<<64, 256, 0, stream>>>(FEAT, Wm1, bm1, Y1);
  k_bn<<<32, 256, 0, stream>>>(Y1, 32, ST1);
  k_mlp2<<<512, 256, 0, stream>>>(Y1, ST1, g1, be1, Wm2, bm2, Y2);
  k_bn<<<512, 256, 0, stream>>>(Y2, 512, ST2);
  k_final<<<128, 256, 0, stream>>>(Y2, ST2, g2, be2, Ws, bs, out);
  k_copy<<<1, 64, 0, stream>>>(wp1, wp2, out);
}